// Round 1
// baseline (477.919 us; speedup 1.0000x reference)
//
#include <hip/hip_runtime.h>

#define N_NODES 32768
#define C_IN 128
#define C_W 32
#define KK 24
#define LL 11
#define SS 5

// ---------------- column stats (sum, sumsq) ----------------
__global__ void k_colstats(const float* __restrict__ src, float* __restrict__ sums,
                           int C, int nrows) {
    int t = threadIdx.x;
    int c = t % C;
    int rpi = blockDim.x / C;
    int r0 = blockIdx.x * rpi + t / C;
    int stride = gridDim.x * rpi;
    float s = 0.f, sq = 0.f;
    for (int r = r0; r < nrows; r += stride) {
        float v = src[(size_t)r * C + c];
        s += v; sq += v * v;
    }
    atomicAdd(&sums[c], s);
    atomicAdd(&sums[C + c], sq);
}

__global__ void k_finalize(const float* __restrict__ sums, const float* __restrict__ g,
                           const float* __restrict__ b, float* __restrict__ ab,
                           int C, float n) {
    int c = threadIdx.x;
    if (c < C) {
        float mean = sums[c] / n;
        float var = sums[C + c] / n - mean * mean;
        float a = g[c] * rsqrtf(var + 1e-5f);
        ab[c] = a;
        ab[C + c] = b[c] - mean * a;
    }
}

// ---------------- input MLP: lrelu(bn1(x)) @ lin1_w ----------------
__global__ void k_mlp1(const float* __restrict__ x, const float* __restrict__ ab1,
                       const float* __restrict__ w1, float* __restrict__ hpre) {
    __shared__ float sx[8][C_IN];
    int t = threadIdx.x;
    int row0 = blockIdx.x * 8;
    for (int idx = t; idx < 8 * C_IN; idx += 256) {
        int r = idx / C_IN, c = idx % C_IN;
        float v = x[(size_t)(row0 + r) * C_IN + c];
        v = ab1[c] * v + ab1[C_IN + c];
        sx[r][c] = v >= 0.f ? v : 0.1f * v;
    }
    __syncthreads();
    int r = t / C_W, cw = t % C_W;
    float acc = 0.f;
    #pragma unroll 4
    for (int c = 0; c < C_IN; ++c)
        acc += sx[r][c] * w1[c * C_W + cw];
    hpre[(size_t)(row0 + r) * C_W + cw] = acc;
}

__global__ void k_bn2(float* __restrict__ hp, const float* __restrict__ ab) {
    int idx = blockIdx.x * blockDim.x + threadIdx.x;
    int c = idx % C_W;
    float v = hp[idx];
    v = ab[c] * v + ab[C_W + c];
    hp[idx] = v >= 0.f ? v : 0.1f * v;
}

// ---------------- CSR build ----------------
__global__ void k_hist(const int* __restrict__ ei, int E, int* __restrict__ counts) {
    int e = blockIdx.x * blockDim.x + threadIdx.x;
    if (e < E) atomicAdd(&counts[ei[E + e]], 1);
}

__global__ void k_scan(const int* __restrict__ counts, int* __restrict__ offsets,
                       int* __restrict__ cursor) {
    __shared__ int sblk[1024];
    int t = threadIdx.x;
    int base = t * 32;
    int loc[32];
    int s = 0;
    #pragma unroll
    for (int j = 0; j < 32; ++j) { loc[j] = s; s += counts[base + j]; }
    sblk[t] = s;
    __syncthreads();
    for (int d = 1; d < 1024; d <<= 1) {
        int v = (t >= d) ? sblk[t - d] : 0;
        __syncthreads();
        sblk[t] += v;
        __syncthreads();
    }
    int blockbase = sblk[t] - s;  // exclusive prefix
    #pragma unroll
    for (int j = 0; j < 32; ++j) {
        int v = blockbase + loc[j];
        offsets[base + j] = v;
        cursor[base + j] = v;
    }
    if (t == 1023) offsets[N_NODES] = sblk[1023];
}

__global__ void k_scatter(const int* __restrict__ ei, int E, int* __restrict__ cursor,
                          int* __restrict__ eids) {
    int e = blockIdx.x * blockDim.x + threadIdx.x;
    if (e < E) {
        int dst = ei[E + e];
        int p = atomicAdd(&cursor[dst], 1);
        eids[p] = e;
    }
}

// ---------------- per-node aggregation + conv projection ----------------
__global__ void __launch_bounds__(256) k_node(
    const int* __restrict__ ei, int E,
    const int* __restrict__ offsets, const int* __restrict__ eids,
    const float* __restrict__ pos, const float* __restrict__ ori,
    const int* __restrict__ seq, const float* __restrict__ h,
    const float* __restrict__ wnw, const float* __restrict__ wnb,
    const float* __restrict__ convw, float* __restrict__ convout) {
    const int i = blockIdx.x;
    const int t = threadIdx.x;
    __shared__ float sRi[9], sPi[3];
    __shared__ int sSrc[16], sSidx[16];
    __shared__ float sDelta[16][8];
    __shared__ float sW[16][KK];
    __shared__ float sH[16][C_W];
    __shared__ float sAgg[768];
    __shared__ float sRed[8][C_W];

    if (t < 9) sRi[t] = ori[i * 9 + t];
    if (t < 3) sPi[t] = pos[i * 3 + t];
    const int beg = offsets[i], end = offsets[i + 1];
    const int seqi = seq[i];
    float a0 = 0.f, a1 = 0.f, a2 = 0.f;   // agg rows t, t+256, t+512
    const int kq = t / 32, cw = t % 32;
    __syncthreads();

    for (int base = beg; base < end; base += 16) {
        int cnt = min(16, end - base);
        if (t < cnt) {
            int e = eids[base + t];
            int src = ei[e];
            sSrc[t] = src;
            int ds = seq[src] - seqi;
            ds = ds < -SS ? -SS : (ds > SS ? SS : ds);
            sSidx[t] = ds + SS;
            float dx = pos[src * 3 + 0] - sPi[0];
            float dy = pos[src * 3 + 1] - sPi[1];
            float dz = pos[src * 3 + 2] - sPi[2];
            float dist = sqrtf(dx * dx + dy * dy + dz * dz);
            float inv = 1.f / (dist + 1e-9f);
            float ux = dx * inv, uy = dy * inv, uz = dz * inv;
            float b0 = ori[src * 9 + 0], b1 = ori[src * 9 + 1], b2 = ori[src * 9 + 2];
            #pragma unroll
            for (int r = 0; r < 3; ++r) {
                float m0 = sRi[r * 3 + 0], m1 = sRi[r * 3 + 1], m2 = sRi[r * 3 + 2];
                sDelta[t][r]     = m0 * ux + m1 * uy + m2 * uz;
                sDelta[t][3 + r] = m0 * b0 + m1 * b1 + m2 * b2;
            }
            sDelta[t][6] = dist * 0.125f;   // dist / R, R=8
        }
        __syncthreads();
        // WeightNet: w[e][k] = lrelu0.2(delta . wnw[sidx] + wnb[sidx])
        for (int idx = t; idx < cnt * KK; idx += 256) {
            int e = idx / KK, k = idx % KK;
            int sb = sSidx[e];
            float acc = wnb[sb * KK + k];
            #pragma unroll
            for (int f = 0; f < 7; ++f)
                acc += sDelta[e][f] * wnw[(sb * 7 + f) * KK + k];
            sW[e][k] = acc >= 0.f ? acc : 0.2f * acc;
        }
        // gather h[src]
        for (int idx = t; idx < cnt * C_W; idx += 256) {
            int e = idx / C_W, c = idx % C_W;
            sH[e][c] = h[(size_t)sSrc[e] * C_W + c];
        }
        __syncthreads();
        for (int e = 0; e < cnt; ++e) {
            float hv = sH[e][cw];
            a0 += sW[e][kq] * hv;
            a1 += sW[e][kq + 8] * hv;
            a2 += sW[e][kq + 16] * hv;
        }
        __syncthreads();
    }
    sAgg[t] = a0; sAgg[t + 256] = a1; sAgg[t + 512] = a2;
    __syncthreads();
    // conv projection: [768] x [768,32]
    float part = 0.f;
    const int g = t / 32, c = t % 32;
    for (int r = g * 96; r < g * 96 + 96; ++r)
        part += sAgg[r] * convw[r * 32 + c];
    sRed[g][c] = part;
    __syncthreads();
    if (t < 32) {
        float v = 0.f;
        #pragma unroll
        for (int gg = 0; gg < 8; ++gg) v += sRed[gg][t];
        convout[(size_t)i * C_W + t] = v;
    }
}

// ---------------- output: lrelu(bn3(conv)) @ lin2_w + x ----------------
__global__ void k_out(const float* __restrict__ conv, const float* __restrict__ ab3,
                      const float* __restrict__ w2, const float* __restrict__ x,
                      float* __restrict__ out) {
    __shared__ float sh[2][C_W];
    int t = threadIdx.x;
    int r = t / C_IN;
    int c = t % C_IN;
    int row = blockIdx.x * 2 + r;
    if (c < C_W) {
        float v = conv[(size_t)row * C_W + c];
        v = ab3[c] * v + ab3[C_W + c];
        sh[r][c] = v >= 0.f ? v : 0.1f * v;
    }
    __syncthreads();
    float acc = x[(size_t)row * C_IN + c];
    #pragma unroll 4
    for (int cw = 0; cw < C_W; ++cw)
        acc += sh[r][cw] * w2[cw * C_IN + c];
    out[(size_t)row * C_IN + c] = acc;
}

extern "C" void kernel_launch(void* const* d_in, const int* in_sizes, int n_in,
                              void* d_out, int out_size, void* d_ws, size_t ws_size,
                              hipStream_t stream) {
    const float* x     = (const float*)d_in[0];
    const float* pos   = (const float*)d_in[1];
    const float* ori   = (const float*)d_in[2];
    const int*   seq   = (const int*)d_in[3];
    const int*   ei    = (const int*)d_in[4];
    const float* bn1g  = (const float*)d_in[5];
    const float* bn1b  = (const float*)d_in[6];
    const float* lin1w = (const float*)d_in[7];
    const float* bn2g  = (const float*)d_in[8];
    const float* bn2b  = (const float*)d_in[9];
    const float* wnw   = (const float*)d_in[10];
    const float* wnb   = (const float*)d_in[11];
    const float* convw = (const float*)d_in[12];
    const float* bn3g  = (const float*)d_in[13];
    const float* bn3b  = (const float*)d_in[14];
    const float* lin2w = (const float*)d_in[15];
    float* out = (float*)d_out;
    const int E = in_sizes[4] / 2;

    char* wsb = (char*)d_ws;
    size_t off = 0;
    auto alloc = [&](size_t bytes) {
        void* p = wsb + off;
        off = (off + bytes + 255) & ~(size_t)255;
        return p;
    };
    float* s1      = (float*)alloc(256 * 4);
    float* s2      = (float*)alloc(64 * 4);
    float* s3      = (float*)alloc(64 * 4);
    float* ab1     = (float*)alloc(256 * 4);
    float* ab2     = (float*)alloc(64 * 4);
    float* ab3     = (float*)alloc(64 * 4);
    int*   counts  = (int*)alloc((size_t)N_NODES * 4);
    int*   offsets = (int*)alloc(((size_t)N_NODES + 1) * 4);
    int*   cursor  = (int*)alloc((size_t)N_NODES * 4);
    int*   eids    = (int*)alloc((size_t)E * 4);
    float* hbuf    = (float*)alloc((size_t)N_NODES * C_W * 4);
    float* convo   = (float*)alloc((size_t)N_NODES * C_W * 4);

    hipMemsetAsync(s1, 0, 256 * 4, stream);
    hipMemsetAsync(s2, 0, 64 * 4, stream);
    hipMemsetAsync(s3, 0, 64 * 4, stream);
    hipMemsetAsync(counts, 0, (size_t)N_NODES * 4, stream);

    k_colstats<<<256, 256, 0, stream>>>(x, s1, C_IN, N_NODES);
    k_finalize<<<1, 128, 0, stream>>>(s1, bn1g, bn1b, ab1, C_IN, (float)N_NODES);
    k_mlp1<<<N_NODES / 8, 256, 0, stream>>>(x, ab1, lin1w, hbuf);
    k_colstats<<<128, 256, 0, stream>>>(hbuf, s2, C_W, N_NODES);
    k_finalize<<<1, 32, 0, stream>>>(s2, bn2g, bn2b, ab2, C_W, (float)N_NODES);
    k_bn2<<<(N_NODES * C_W) / 256, 256, 0, stream>>>(hbuf, ab2);
    k_hist<<<(E + 255) / 256, 256, 0, stream>>>(ei, E, counts);
    k_scan<<<1, 1024, 0, stream>>>(counts, offsets, cursor);
    k_scatter<<<(E + 255) / 256, 256, 0, stream>>>(ei, E, cursor, eids);
    k_node<<<N_NODES, 256, 0, stream>>>(ei, E, offsets, eids, pos, ori, seq,
                                        hbuf, wnw, wnb, convw, convo);
    k_colstats<<<128, 256, 0, stream>>>(convo, s3, C_W, N_NODES);
    k_finalize<<<1, 32, 0, stream>>>(s3, bn3g, bn3b, ab3, C_W, (float)N_NODES);
    k_out<<<N_NODES / 2, 256, 0, stream>>>(convo, ab3, lin2w, x, out);
}

// Round 2
// 428.979 us; speedup vs baseline: 1.1141x; 1.1141x over previous
//
#include <hip/hip_runtime.h>

#define N_NODES 32768
#define C_IN 128
#define C_W 32
#define KK 24
#define SS 5
#define GG 8      // nodes per k_node block
#define BB 64     // edge batch

// ---------------- column stats (sum, sumsq) ----------------
__global__ void k_colstats(const float* __restrict__ src, float* __restrict__ sums,
                           int C, int nrows) {
    int t = threadIdx.x;
    int c = t % C;
    int rpi = blockDim.x / C;
    int r0 = blockIdx.x * rpi + t / C;
    int stride = gridDim.x * rpi;
    float s = 0.f, sq = 0.f;
    for (int r = r0; r < nrows; r += stride) {
        float v = src[(size_t)r * C + c];
        s += v; sq += v * v;
    }
    atomicAdd(&sums[c], s);
    atomicAdd(&sums[C + c], sq);
}

// ---------------- input MLP: lrelu(bn1(x)) @ lin1_w ----------------
__global__ void __launch_bounds__(256) k_mlp1(
        const float* __restrict__ x, const float* __restrict__ s1,
        const float* __restrict__ g1, const float* __restrict__ b1,
        const float* __restrict__ w1, float* __restrict__ hpre) {
    __shared__ float sAB[2][C_IN];
    __shared__ float sx[32][C_IN + 4];
    __shared__ float sw[C_IN][C_W];
    const int t = threadIdx.x;
    const int row0 = blockIdx.x * 32;
    if (t < C_IN) {
        float mean = s1[t] * (1.f / N_NODES);
        float var = s1[C_IN + t] * (1.f / N_NODES) - mean * mean;
        float a = g1[t] * rsqrtf(var + 1e-5f);
        sAB[0][t] = a; sAB[1][t] = b1[t] - mean * a;
    }
    for (int idx = t; idx < C_IN * C_W; idx += 256)
        sw[idx / C_W][idx % C_W] = w1[idx];
    __syncthreads();
    for (int idx = t; idx < 32 * 32; idx += 256) {
        int r = idx >> 5, cq = idx & 31;
        float4 v = *(const float4*)&x[(size_t)(row0 + r) * C_IN + cq * 4];
        float* d = &sx[r][cq * 4];
        float a0 = sAB[0][cq*4+0]*v.x + sAB[1][cq*4+0];
        float a1 = sAB[0][cq*4+1]*v.y + sAB[1][cq*4+1];
        float a2 = sAB[0][cq*4+2]*v.z + sAB[1][cq*4+2];
        float a3 = sAB[0][cq*4+3]*v.w + sAB[1][cq*4+3];
        d[0] = a0 >= 0.f ? a0 : 0.1f * a0;
        d[1] = a1 >= 0.f ? a1 : 0.1f * a1;
        d[2] = a2 >= 0.f ? a2 : 0.1f * a2;
        d[3] = a3 >= 0.f ? a3 : 0.1f * a3;
    }
    __syncthreads();
    const int r = t >> 3, c0 = (t & 7) * 4;
    float ac0 = 0.f, ac1 = 0.f, ac2 = 0.f, ac3 = 0.f;
    #pragma unroll 8
    for (int cc = 0; cc < C_IN; ++cc) {
        float xv = sx[r][cc];
        float4 wv = *(const float4*)&sw[cc][c0];
        ac0 += xv * wv.x; ac1 += xv * wv.y; ac2 += xv * wv.z; ac3 += xv * wv.w;
    }
    float4 o; o.x = ac0; o.y = ac1; o.z = ac2; o.w = ac3;
    *(float4*)&hpre[(size_t)(row0 + r) * C_W + c0] = o;
}

// ---------------- CSR build ----------------
__global__ void k_hist(const int* __restrict__ ei, int E, int* __restrict__ counts) {
    int e = blockIdx.x * blockDim.x + threadIdx.x;
    if (e < E) atomicAdd(&counts[ei[E + e]], 1);
}

__global__ void k_scan(const int* __restrict__ counts, int* __restrict__ offsets,
                       int* __restrict__ cursor) {
    __shared__ int sblk[1024];
    int t = threadIdx.x;
    int base = t * 32;
    int loc[32];
    int s = 0;
    #pragma unroll
    for (int j = 0; j < 32; ++j) { loc[j] = s; s += counts[base + j]; }
    sblk[t] = s;
    __syncthreads();
    for (int d = 1; d < 1024; d <<= 1) {
        int v = (t >= d) ? sblk[t - d] : 0;
        __syncthreads();
        sblk[t] += v;
        __syncthreads();
    }
    int blockbase = sblk[t] - s;
    #pragma unroll
    for (int j = 0; j < 32; ++j) {
        int v = blockbase + loc[j];
        offsets[base + j] = v;
        cursor[base + j] = v;
    }
    if (t == 1023) offsets[N_NODES] = sblk[1023];
}

__global__ void k_scatter(const int* __restrict__ ei, int E, int* __restrict__ cursor,
                          int* __restrict__ eids) {
    int e = blockIdx.x * blockDim.x + threadIdx.x;
    if (e < E) {
        int dst = ei[E + e];
        int p = atomicAdd(&cursor[dst], 1);
        eids[p] = e;
    }
}

// ---------------- per-node aggregation + conv projection (8 nodes/block) ----------------
__global__ void __launch_bounds__(256) k_node(
    const int* __restrict__ ei, int E,
    const int* __restrict__ offsets, const int* __restrict__ eids,
    const float* __restrict__ pos, const float* __restrict__ ori,
    const int* __restrict__ seq, const float* __restrict__ hpre,
    const float* __restrict__ s2, const float* __restrict__ g2, const float* __restrict__ b2,
    const float* __restrict__ wnw, const float* __restrict__ wnb,
    const float* __restrict__ convw, float* __restrict__ convout) {
    const int i0 = blockIdx.x * GG;
    const int t = threadIdx.x;
    __shared__ float sAB2[2][C_W];
    __shared__ int sOff[GG + 1];
    __shared__ int sSrc[BB], sSid[BB];
    __shared__ float sDelta[BB][8];
    __shared__ float sW[BB][KK];
    __shared__ float sH[BB][C_W];
    __shared__ float sAgg[GG][KK * C_W];

    if (t < C_W) {
        float mean = s2[t] * (1.f / N_NODES);
        float var = s2[C_W + t] * (1.f / N_NODES) - mean * mean;
        float a = g2[t] * rsqrtf(var + 1e-5f);
        sAB2[0][t] = a; sAB2[1][t] = b2[t] - mean * a;
    }
    if (t <= GG) sOff[t] = offsets[i0 + t];
    __syncthreads();
    const int beg = sOff[0], endAll = sOff[GG];
    const int g = t >> 5, c = t & 31;
    const int myBeg = sOff[g], myEnd = sOff[g + 1];
    float a[KK];
    #pragma unroll
    for (int k = 0; k < KK; ++k) a[k] = 0.f;

    for (int base = beg; base < endAll; base += BB) {
        const int cnt = min(BB, endAll - base);
        if (t < cnt) {
            int e = eids[base + t];
            int src = ei[e];
            int dst = ei[E + e];
            sSrc[t] = src;
            int ds = seq[src] - seq[dst];
            ds = ds < -SS ? -SS : (ds > SS ? SS : ds);
            sSid[t] = ds + SS;
            float dx = pos[src * 3 + 0] - pos[dst * 3 + 0];
            float dy = pos[src * 3 + 1] - pos[dst * 3 + 1];
            float dz = pos[src * 3 + 2] - pos[dst * 3 + 2];
            float dist = sqrtf(dx * dx + dy * dy + dz * dz);
            float inv = 1.f / (dist + 1e-9f);
            float ux = dx * inv, uy = dy * inv, uz = dz * inv;
            float b0 = ori[src * 9 + 0], bb1 = ori[src * 9 + 1], bb2 = ori[src * 9 + 2];
            #pragma unroll
            for (int r = 0; r < 3; ++r) {
                float m0 = ori[dst * 9 + r * 3 + 0];
                float m1 = ori[dst * 9 + r * 3 + 1];
                float m2 = ori[dst * 9 + r * 3 + 2];
                sDelta[t][r]     = m0 * ux + m1 * uy + m2 * uz;
                sDelta[t][3 + r] = m0 * b0 + m1 * bb1 + m2 * bb2;
            }
            sDelta[t][6] = dist * 0.125f;
        }
        __syncthreads();
        for (int idx = t; idx < cnt * KK; idx += 256) {
            int e = idx / KK, k = idx % KK;
            int sb = sSid[e];
            float acc = wnb[sb * KK + k];
            #pragma unroll
            for (int f = 0; f < 7; ++f)
                acc += sDelta[e][f] * wnw[(sb * 7 + f) * KK + k];
            sW[e][k] = acc >= 0.f ? acc : 0.2f * acc;
        }
        for (int idx = t; idx < cnt * 8; idx += 256) {
            int e = idx >> 3, q = idx & 7;
            float4 hv = *(const float4*)&hpre[(size_t)sSrc[e] * C_W + q * 4];
            float v0 = sAB2[0][q*4+0]*hv.x + sAB2[1][q*4+0];
            float v1 = sAB2[0][q*4+1]*hv.y + sAB2[1][q*4+1];
            float v2 = sAB2[0][q*4+2]*hv.z + sAB2[1][q*4+2];
            float v3 = sAB2[0][q*4+3]*hv.w + sAB2[1][q*4+3];
            float4 o;
            o.x = v0 >= 0.f ? v0 : 0.1f * v0;
            o.y = v1 >= 0.f ? v1 : 0.1f * v1;
            o.z = v2 >= 0.f ? v2 : 0.1f * v2;
            o.w = v3 >= 0.f ? v3 : 0.1f * v3;
            *(float4*)&sH[e][q * 4] = o;
        }
        __syncthreads();
        const int lo = max(myBeg, base), hi = min(myEnd, base + cnt);
        for (int p = lo; p < hi; ++p) {
            int e = p - base;
            float hv = sH[e][c];
            const float4* wr = (const float4*)&sW[e][0];
            float4 w0 = wr[0], w1 = wr[1], w2 = wr[2];
            float4 w3 = wr[3], w4 = wr[4], w5 = wr[5];
            a[0]  += w0.x * hv; a[1]  += w0.y * hv; a[2]  += w0.z * hv; a[3]  += w0.w * hv;
            a[4]  += w1.x * hv; a[5]  += w1.y * hv; a[6]  += w1.z * hv; a[7]  += w1.w * hv;
            a[8]  += w2.x * hv; a[9]  += w2.y * hv; a[10] += w2.z * hv; a[11] += w2.w * hv;
            a[12] += w3.x * hv; a[13] += w3.y * hv; a[14] += w3.z * hv; a[15] += w3.w * hv;
            a[16] += w4.x * hv; a[17] += w4.y * hv; a[18] += w4.z * hv; a[19] += w4.w * hv;
            a[20] += w5.x * hv; a[21] += w5.y * hv; a[22] += w5.z * hv; a[23] += w5.w * hv;
        }
        __syncthreads();
    }
    #pragma unroll
    for (int k = 0; k < KK; ++k) sAgg[g][k * C_W + c] = a[k];
    __syncthreads();
    // projection: out[g][c] = sum_r sAgg[g][r] * convw[r*32+c]
    float p0 = 0.f, p1 = 0.f;
    for (int r = 0; r < KK * C_W; r += 8) {
        float4 v0 = *(const float4*)&sAgg[g][r];
        float4 v1 = *(const float4*)&sAgg[g][r + 4];
        p0 += v0.x * convw[(r + 0) * 32 + c] + v0.y * convw[(r + 1) * 32 + c]
            + v0.z * convw[(r + 2) * 32 + c] + v0.w * convw[(r + 3) * 32 + c];
        p1 += v1.x * convw[(r + 4) * 32 + c] + v1.y * convw[(r + 5) * 32 + c]
            + v1.z * convw[(r + 6) * 32 + c] + v1.w * convw[(r + 7) * 32 + c];
    }
    convout[(size_t)(i0 + g) * C_W + c] = p0 + p1;
}

// ---------------- output: lrelu(bn3(conv)) @ lin2_w + x ----------------
__global__ void __launch_bounds__(256) k_out(
        const float* __restrict__ conv, const float* __restrict__ s3,
        const float* __restrict__ g3, const float* __restrict__ b3,
        const float* __restrict__ w2, const float* __restrict__ x,
        float* __restrict__ out) {
    __shared__ float sAB[2][C_W];
    __shared__ float sh[8][C_W];
    __shared__ float sw2[C_W][C_IN];
    const int t = threadIdx.x;
    const int row0 = blockIdx.x * 8;
    if (t < C_W) {
        float mean = s3[t] * (1.f / N_NODES);
        float var = s3[C_W + t] * (1.f / N_NODES) - mean * mean;
        float a = g3[t] * rsqrtf(var + 1e-5f);
        sAB[0][t] = a; sAB[1][t] = b3[t] - mean * a;
    }
    for (int idx = t; idx < C_W * C_IN; idx += 256)
        sw2[idx >> 7][idx & 127] = w2[idx];
    __syncthreads();
    {
        float v = conv[(size_t)row0 * C_W + t];
        int r = t >> 5, cc = t & 31;
        v = sAB[0][cc] * v + sAB[1][cc];
        sh[r][cc] = v >= 0.f ? v : 0.1f * v;
    }
    __syncthreads();
    const int c = t & 127, rq = t >> 7;
    float acc[4];
    #pragma unroll
    for (int j = 0; j < 4; ++j)
        acc[j] = x[(size_t)(row0 + rq + j * 2) * C_IN + c];
    #pragma unroll 4
    for (int cw = 0; cw < C_W; ++cw) {
        float wv = sw2[cw][c];
        #pragma unroll
        for (int j = 0; j < 4; ++j)
            acc[j] += sh[rq + j * 2][cw] * wv;
    }
    #pragma unroll
    for (int j = 0; j < 4; ++j)
        out[(size_t)(row0 + rq + j * 2) * C_IN + c] = acc[j];
}

extern "C" void kernel_launch(void* const* d_in, const int* in_sizes, int n_in,
                              void* d_out, int out_size, void* d_ws, size_t ws_size,
                              hipStream_t stream) {
    const float* x     = (const float*)d_in[0];
    const float* pos   = (const float*)d_in[1];
    const float* ori   = (const float*)d_in[2];
    const int*   seq   = (const int*)d_in[3];
    const int*   ei    = (const int*)d_in[4];
    const float* bn1g  = (const float*)d_in[5];
    const float* bn1b  = (const float*)d_in[6];
    const float* lin1w = (const float*)d_in[7];
    const float* bn2g  = (const float*)d_in[8];
    const float* bn2b  = (const float*)d_in[9];
    const float* wnw   = (const float*)d_in[10];
    const float* wnb   = (const float*)d_in[11];
    const float* convw = (const float*)d_in[12];
    const float* bn3g  = (const float*)d_in[13];
    const float* bn3b  = (const float*)d_in[14];
    const float* lin2w = (const float*)d_in[15];
    float* out = (float*)d_out;
    const int E = in_sizes[4] / 2;

    char* wsb = (char*)d_ws;
    size_t off = 0;
    auto alloc = [&](size_t bytes) {
        void* p = wsb + off;
        off = (off + bytes + 255) & ~(size_t)255;
        return p;
    };
    // zero-init region: s1, s2, s3, counts contiguous at front
    float* s1      = (float*)alloc(256 * 4);
    float* s2      = (float*)alloc(64 * 4);
    float* s3      = (float*)alloc(64 * 4);
    int*   counts  = (int*)alloc((size_t)N_NODES * 4);
    size_t zero_bytes = off;
    int*   offsets = (int*)alloc(((size_t)N_NODES + 1) * 4);
    int*   cursor  = (int*)alloc((size_t)N_NODES * 4);
    int*   eids    = (int*)alloc((size_t)E * 4);
    float* hpre    = (float*)alloc((size_t)N_NODES * C_W * 4);
    float* convo   = (float*)alloc((size_t)N_NODES * C_W * 4);

    hipMemsetAsync(wsb, 0, zero_bytes, stream);

    k_colstats<<<256, 256, 0, stream>>>(x, s1, C_IN, N_NODES);
    k_mlp1<<<N_NODES / 32, 256, 0, stream>>>(x, s1, bn1g, bn1b, lin1w, hpre);
    k_colstats<<<128, 256, 0, stream>>>(hpre, s2, C_W, N_NODES);
    k_hist<<<(E + 255) / 256, 256, 0, stream>>>(ei, E, counts);
    k_scan<<<1, 1024, 0, stream>>>(counts, offsets, cursor);
    k_scatter<<<(E + 255) / 256, 256, 0, stream>>>(ei, E, cursor, eids);
    k_node<<<N_NODES / GG, 256, 0, stream>>>(ei, E, offsets, eids, pos, ori, seq,
                                             hpre, s2, bn2g, bn2b, wnw, wnb, convw, convo);
    k_colstats<<<128, 256, 0, stream>>>(convo, s3, C_W, N_NODES);
    k_out<<<N_NODES / 8, 256, 0, stream>>>(convo, s3, bn3g, bn3b, lin2w, x, out);
}

// Round 3
// 290.105 us; speedup vs baseline: 1.6474x; 1.4787x over previous
//
#include <hip/hip_runtime.h>

#define N_NODES 32768
#define C_IN 128
#define C_W 32
#define KK 24
#define SS 5
#define GG 8      // nodes per k_node block

// ---------------- colstats(x) for BN1 + edge histogram ----------------
__global__ void __launch_bounds__(256) k_pre(
        const float* __restrict__ x, float* __restrict__ s1,
        const int* __restrict__ ei, int E, int* __restrict__ counts) {
    int t = threadIdx.x;
    int c = t % C_IN;
    int r0 = blockIdx.x * 2 + t / C_IN;
    float s = 0.f, sq = 0.f;
    for (int r = r0; r < N_NODES; r += 512) {
        float v = x[(size_t)r * C_IN + c];
        s += v; sq += v * v;
    }
    atomicAdd(&s1[c], s);
    atomicAdd(&s1[C_IN + c], sq);
    for (int e = blockIdx.x * 256 + t; e < E; e += 256 * 256)
        atomicAdd(&counts[ei[E + e]], 1);
}

// ---------------- input MLP: lrelu(bn1(x)) @ lin1_w (+ BN2 stats) ----------------
__global__ void __launch_bounds__(256) k_mlp1(
        const float* __restrict__ x, const float* __restrict__ s1,
        const float* __restrict__ g1, const float* __restrict__ b1,
        const float* __restrict__ w1, float* __restrict__ hpre,
        float* __restrict__ s2sh) {
    __shared__ float sAB[2][C_IN];
    __shared__ float sx[32][C_IN + 4];
    __shared__ float sw[C_IN][C_W];
    const int t = threadIdx.x;
    const int row0 = blockIdx.x * 32;
    if (t < C_IN) {
        float mean = s1[t] * (1.f / N_NODES);
        float var = s1[C_IN + t] * (1.f / N_NODES) - mean * mean;
        float a = g1[t] * rsqrtf(var + 1e-5f);
        sAB[0][t] = a; sAB[1][t] = b1[t] - mean * a;
    }
    for (int idx = t; idx < C_IN * C_W; idx += 256)
        sw[idx / C_W][idx % C_W] = w1[idx];
    __syncthreads();
    for (int idx = t; idx < 32 * 32; idx += 256) {
        int r = idx >> 5, cq = idx & 31;
        float4 v = *(const float4*)&x[(size_t)(row0 + r) * C_IN + cq * 4];
        float* d = &sx[r][cq * 4];
        float a0 = sAB[0][cq*4+0]*v.x + sAB[1][cq*4+0];
        float a1 = sAB[0][cq*4+1]*v.y + sAB[1][cq*4+1];
        float a2 = sAB[0][cq*4+2]*v.z + sAB[1][cq*4+2];
        float a3 = sAB[0][cq*4+3]*v.w + sAB[1][cq*4+3];
        d[0] = a0 >= 0.f ? a0 : 0.1f * a0;
        d[1] = a1 >= 0.f ? a1 : 0.1f * a1;
        d[2] = a2 >= 0.f ? a2 : 0.1f * a2;
        d[3] = a3 >= 0.f ? a3 : 0.1f * a3;
    }
    __syncthreads();
    const int r = t >> 3, c0 = (t & 7) * 4;
    float ac0 = 0.f, ac1 = 0.f, ac2 = 0.f, ac3 = 0.f;
    #pragma unroll 8
    for (int cc = 0; cc < C_IN; ++cc) {
        float xv = sx[r][cc];
        float4 wv = *(const float4*)&sw[cc][c0];
        ac0 += xv * wv.x; ac1 += xv * wv.y; ac2 += xv * wv.z; ac3 += xv * wv.w;
    }
    float4 o; o.x = ac0; o.y = ac1; o.z = ac2; o.w = ac3;
    *(float4*)&hpre[(size_t)(row0 + r) * C_W + c0] = o;
    __syncthreads();           // sx reads done; reuse sx for column stats
    sx[r][c0] = ac0; sx[r][c0+1] = ac1; sx[r][c0+2] = ac2; sx[r][c0+3] = ac3;
    __syncthreads();
    if (t < C_W) {
        float s = 0.f, sq = 0.f;
        #pragma unroll
        for (int rr = 0; rr < 32; ++rr) {
            float v = sx[rr][t];
            s += v; sq += v * v;
        }
        int sh = (blockIdx.x & 7) * 64;
        atomicAdd(&s2sh[sh + t], s);
        atomicAdd(&s2sh[sh + C_W + t], sq);
    }
}

// ---------------- hierarchical scan ----------------
__global__ void __launch_bounds__(1024) k_scan1(
        const int* __restrict__ counts, int* __restrict__ scanned,
        int* __restrict__ blockSums) {
    __shared__ int s[1024];
    int t = threadIdx.x;
    int i = blockIdx.x * 1024 + t;
    int v = counts[i];
    s[t] = v;
    __syncthreads();
    for (int d = 1; d < 1024; d <<= 1) {
        int u = (t >= d) ? s[t - d] : 0;
        __syncthreads();
        s[t] += u;
        __syncthreads();
    }
    scanned[i] = s[t] - v;
    if (t == 1023) blockSums[blockIdx.x] = s[1023];
}

__global__ void k_scan2(int* __restrict__ blockSums, int* __restrict__ blockOff,
                        int* __restrict__ offsets) {
    __shared__ int s[32];
    int t = threadIdx.x;
    int v = blockSums[t];
    s[t] = v;
    __syncthreads();
    for (int d = 1; d < 32; d <<= 1) {
        int u = (t >= d) ? s[t - d] : 0;
        __syncthreads();
        s[t] += u;
        __syncthreads();
    }
    blockOff[t] = s[t] - v;
    if (t == 31) offsets[N_NODES] = s[31];
}

__global__ void __launch_bounds__(1024) k_scan3(
        const int* __restrict__ scanned, const int* __restrict__ blockOff,
        int* __restrict__ offsets, int* __restrict__ cursor) {
    int t = threadIdx.x;
    int i = blockIdx.x * 1024 + t;
    int v = scanned[i] + blockOff[blockIdx.x];
    offsets[i] = v;
    cursor[i] = v;
}

// ---------------- edge kernel: WeightNet + scatter to CSR slots ----------------
__global__ void __launch_bounds__(256) k_edge(
        const int* __restrict__ ei, int E,
        const float* __restrict__ pos, const float* __restrict__ ori,
        const int* __restrict__ seq,
        const float* __restrict__ wnw, const float* __restrict__ wnb,
        int* __restrict__ cursor, int* __restrict__ srcPerm,
        float* __restrict__ wPerm) {
    __shared__ float sWnw[11][169];   // padded stride vs 168: spreads sb across banks
    __shared__ float sWnb[11][24];
    const int t = threadIdx.x;
    for (int idx = t; idx < 11 * 168; idx += 256)
        sWnw[idx / 168][idx % 168] = wnw[idx];
    for (int idx = t; idx < 11 * 24; idx += 256)
        sWnb[idx / 24][idx % 24] = wnb[idx];
    __syncthreads();
    const int e = blockIdx.x * 256 + t;
    if (e >= E) return;
    const int src = ei[e];
    const int dst = ei[E + e];
    int ds = seq[src] - seq[dst];
    ds = ds < -SS ? -SS : (ds > SS ? SS : ds);
    const int sb = ds + SS;
    float dx = pos[src * 3 + 0] - pos[dst * 3 + 0];
    float dy = pos[src * 3 + 1] - pos[dst * 3 + 1];
    float dz = pos[src * 3 + 2] - pos[dst * 3 + 2];
    float dist = sqrtf(dx * dx + dy * dy + dz * dz);
    float inv = 1.f / (dist + 1e-9f);
    float ux = dx * inv, uy = dy * inv, uz = dz * inv;
    float b0 = ori[src * 9 + 0], b1 = ori[src * 9 + 1], b2 = ori[src * 9 + 2];
    float delta[7];
    #pragma unroll
    for (int r = 0; r < 3; ++r) {
        float m0 = ori[dst * 9 + r * 3 + 0];
        float m1 = ori[dst * 9 + r * 3 + 1];
        float m2 = ori[dst * 9 + r * 3 + 2];
        delta[r]     = m0 * ux + m1 * uy + m2 * uz;
        delta[3 + r] = m0 * b0 + m1 * b1 + m2 * b2;
    }
    delta[6] = dist * 0.125f;
    float w[KK];
    #pragma unroll
    for (int k = 0; k < KK; ++k) {
        float acc = sWnb[sb][k];
        #pragma unroll
        for (int f = 0; f < 7; ++f)
            acc += delta[f] * sWnw[sb][f * 24 + k];
        w[k] = acc >= 0.f ? acc : 0.2f * acc;
    }
    const int p = atomicAdd(&cursor[dst], 1);
    srcPerm[p] = src;
    float4* wp = (float4*)(wPerm + (size_t)p * KK);
    #pragma unroll
    for (int q = 0; q < 6; ++q) {
        float4 o; o.x = w[q*4]; o.y = w[q*4+1]; o.z = w[q*4+2]; o.w = w[q*4+3];
        wp[q] = o;
    }
}

// ---------------- aggregation + conv projection (+ BN3 stats) ----------------
__global__ void __launch_bounds__(256) k_node(
    const int* __restrict__ offsets, const int* __restrict__ srcPerm,
    const float* __restrict__ wPerm, const float* __restrict__ hpre,
    const float* __restrict__ s2sh, const float* __restrict__ g2,
    const float* __restrict__ b2, const float* __restrict__ convw,
    float* __restrict__ convout, float* __restrict__ s3sh) {
    __shared__ float sA2[C_W], sB2[C_W];
    __shared__ int sOff[GG + 1];
    __shared__ float sAgg[GG][KK * C_W];
    __shared__ float sRv[GG][C_W], sRq[GG][C_W];
    const int i0 = blockIdx.x * GG;
    const int t = threadIdx.x;
    if (t < C_W) {
        float s = 0.f, sq = 0.f;
        #pragma unroll
        for (int j = 0; j < 8; ++j) {
            s  += s2sh[j * 64 + t];
            sq += s2sh[j * 64 + C_W + t];
        }
        float mean = s * (1.f / N_NODES);
        float var = sq * (1.f / N_NODES) - mean * mean;
        float a = g2[t] * rsqrtf(var + 1e-5f);
        sA2[t] = a; sB2[t] = b2[t] - mean * a;
    }
    if (t <= GG) sOff[t] = offsets[i0 + t];
    __syncthreads();
    const int g = t >> 5, c = t & 31;
    const float bnA = sA2[c], bnB = sB2[c];
    int p = sOff[g];
    const int pEnd = sOff[g + 1];
    float a[KK];
    #pragma unroll
    for (int k = 0; k < KK; ++k) a[k] = 0.f;

    int srcCur = (p < pEnd) ? srcPerm[p] : 0;
    for (; p < pEnd; ++p) {
        int srcNxt = (p + 1 < pEnd) ? srcPerm[p + 1] : 0;
        float hr = hpre[(size_t)srcCur * C_W + c];
        const float4* wr = (const float4*)(wPerm + (size_t)p * KK);
        float4 w0 = wr[0], w1 = wr[1], w2 = wr[2];
        float4 w3 = wr[3], w4 = wr[4], w5 = wr[5];
        float v = bnA * hr + bnB;
        v = v >= 0.f ? v : 0.1f * v;
        a[0]  += w0.x * v; a[1]  += w0.y * v; a[2]  += w0.z * v; a[3]  += w0.w * v;
        a[4]  += w1.x * v; a[5]  += w1.y * v; a[6]  += w1.z * v; a[7]  += w1.w * v;
        a[8]  += w2.x * v; a[9]  += w2.y * v; a[10] += w2.z * v; a[11] += w2.w * v;
        a[12] += w3.x * v; a[13] += w3.y * v; a[14] += w3.z * v; a[15] += w3.w * v;
        a[16] += w4.x * v; a[17] += w4.y * v; a[18] += w4.z * v; a[19] += w4.w * v;
        a[20] += w5.x * v; a[21] += w5.y * v; a[22] += w5.z * v; a[23] += w5.w * v;
        srcCur = srcNxt;
    }
    #pragma unroll
    for (int k = 0; k < KK; ++k) sAgg[g][k * C_W + c] = a[k];
    __syncthreads();
    float p0 = 0.f, p1 = 0.f;
    for (int r = 0; r < KK * C_W; r += 8) {
        float4 v0 = *(const float4*)&sAgg[g][r];
        float4 v1 = *(const float4*)&sAgg[g][r + 4];
        p0 += v0.x * convw[(r + 0) * 32 + c] + v0.y * convw[(r + 1) * 32 + c]
            + v0.z * convw[(r + 2) * 32 + c] + v0.w * convw[(r + 3) * 32 + c];
        p1 += v1.x * convw[(r + 4) * 32 + c] + v1.y * convw[(r + 5) * 32 + c]
            + v1.z * convw[(r + 6) * 32 + c] + v1.w * convw[(r + 7) * 32 + c];
    }
    float v = p0 + p1;
    convout[(size_t)(i0 + g) * C_W + c] = v;
    sRv[g][c] = v; sRq[g][c] = v * v;
    __syncthreads();
    if (t < 64) {
        int cc = t & 31;
        bool isq = t >= C_W;
        float s = 0.f;
        #pragma unroll
        for (int gg = 0; gg < GG; ++gg)
            s += isq ? sRq[gg][cc] : sRv[gg][cc];
        atomicAdd(&s3sh[(blockIdx.x & 7) * 64 + t], s);
    }
}

// ---------------- output: lrelu(bn3(conv)) @ lin2_w + x ----------------
__global__ void __launch_bounds__(256) k_out(
        const float* __restrict__ conv, const float* __restrict__ s3sh,
        const float* __restrict__ g3, const float* __restrict__ b3,
        const float* __restrict__ w2, const float* __restrict__ x,
        float* __restrict__ out) {
    __shared__ float sAB[2][C_W];
    __shared__ float sh[8][C_W];
    __shared__ float sw2[C_W][C_IN];
    const int t = threadIdx.x;
    const int row0 = blockIdx.x * 8;
    if (t < C_W) {
        float s = 0.f, sq = 0.f;
        #pragma unroll
        for (int j = 0; j < 8; ++j) {
            s  += s3sh[j * 64 + t];
            sq += s3sh[j * 64 + C_W + t];
        }
        float mean = s * (1.f / N_NODES);
        float var = sq * (1.f / N_NODES) - mean * mean;
        float a = g3[t] * rsqrtf(var + 1e-5f);
        sAB[0][t] = a; sAB[1][t] = b3[t] - mean * a;
    }
    for (int idx = t; idx < C_W * C_IN; idx += 256)
        sw2[idx >> 7][idx & 127] = w2[idx];
    __syncthreads();
    {
        float v = conv[(size_t)row0 * C_W + t];
        int r = t >> 5, cc = t & 31;
        v = sAB[0][cc] * v + sAB[1][cc];
        sh[r][cc] = v >= 0.f ? v : 0.1f * v;
    }
    __syncthreads();
    const int c = t & 127, rq = t >> 7;
    float acc[4];
    #pragma unroll
    for (int j = 0; j < 4; ++j)
        acc[j] = x[(size_t)(row0 + rq + j * 2) * C_IN + c];
    #pragma unroll 4
    for (int cw = 0; cw < C_W; ++cw) {
        float wv = sw2[cw][c];
        #pragma unroll
        for (int j = 0; j < 4; ++j)
            acc[j] += sh[rq + j * 2][cw] * wv;
    }
    #pragma unroll
    for (int j = 0; j < 4; ++j)
        out[(size_t)(row0 + rq + j * 2) * C_IN + c] = acc[j];
}

extern "C" void kernel_launch(void* const* d_in, const int* in_sizes, int n_in,
                              void* d_out, int out_size, void* d_ws, size_t ws_size,
                              hipStream_t stream) {
    const float* x     = (const float*)d_in[0];
    const float* pos   = (const float*)d_in[1];
    const float* ori   = (const float*)d_in[2];
    const int*   seq   = (const int*)d_in[3];
    const int*   ei    = (const int*)d_in[4];
    const float* bn1g  = (const float*)d_in[5];
    const float* bn1b  = (const float*)d_in[6];
    const float* lin1w = (const float*)d_in[7];
    const float* bn2g  = (const float*)d_in[8];
    const float* bn2b  = (const float*)d_in[9];
    const float* wnw   = (const float*)d_in[10];
    const float* wnb   = (const float*)d_in[11];
    const float* convw = (const float*)d_in[12];
    const float* bn3g  = (const float*)d_in[13];
    const float* bn3b  = (const float*)d_in[14];
    const float* lin2w = (const float*)d_in[15];
    float* out = (float*)d_out;
    const int E = in_sizes[4] / 2;

    char* wsb = (char*)d_ws;
    size_t off = 0;
    auto alloc = [&](size_t bytes) {
        void* p = wsb + off;
        off = (off + bytes + 255) & ~(size_t)255;
        return p;
    };
    // zero-init region at front: s1, s2sh, s3sh, counts
    float* s1      = (float*)alloc(256 * 4);
    float* s2sh    = (float*)alloc(512 * 4);
    float* s3sh    = (float*)alloc(512 * 4);
    int*   counts  = (int*)alloc((size_t)N_NODES * 4);
    size_t zero_bytes = off;
    int*   scanned = (int*)alloc((size_t)N_NODES * 4);
    int*   bsums   = (int*)alloc(64 * 4);
    int*   boff    = (int*)alloc(64 * 4);
    int*   offsets = (int*)alloc(((size_t)N_NODES + 1) * 4);
    int*   cursor  = (int*)alloc((size_t)N_NODES * 4);
    int*   srcPerm = (int*)alloc((size_t)E * 4);
    float* hpre    = (float*)alloc((size_t)N_NODES * C_W * 4);
    float* convo   = (float*)alloc((size_t)N_NODES * C_W * 4);
    float* wPerm   = (float*)alloc((size_t)E * KK * 4);

    hipMemsetAsync(wsb, 0, zero_bytes, stream);

    k_pre<<<256, 256, 0, stream>>>(x, s1, ei, E, counts);
    k_mlp1<<<N_NODES / 32, 256, 0, stream>>>(x, s1, bn1g, bn1b, lin1w, hpre, s2sh);
    k_scan1<<<32, 1024, 0, stream>>>(counts, scanned, bsums);
    k_scan2<<<1, 32, 0, stream>>>(bsums, boff, offsets);
    k_scan3<<<32, 1024, 0, stream>>>(scanned, boff, offsets, cursor);
    k_edge<<<(E + 255) / 256, 256, 0, stream>>>(ei, E, pos, ori, seq, wnw, wnb,
                                                cursor, srcPerm, wPerm);
    k_node<<<N_NODES / GG, 256, 0, stream>>>(offsets, srcPerm, wPerm, hpre,
                                             s2sh, bn2g, bn2b, convw, convo, s3sh);
    k_out<<<N_NODES / 8, 256, 0, stream>>>(convo, s3sh, bn3g, bn3b, lin2w, x, out);
}

// Round 4
// 285.994 us; speedup vs baseline: 1.6711x; 1.0144x over previous
//
#include <hip/hip_runtime.h>

#define N_NODES 32768
#define C_IN 128
#define C_W 32
#define KK 24
#define SS 5
#define GG 8      // nodes per k_node block

#define LD6(W, PTR) do { const float4* _p = (const float4*)(PTR); \
  W[0]=_p[0]; W[1]=_p[1]; W[2]=_p[2]; W[3]=_p[3]; W[4]=_p[4]; W[5]=_p[5]; } while(0)

#define ACC24(W, V) do { float _v = (V); \
  a[0]+=W[0].x*_v;  a[1]+=W[0].y*_v;  a[2]+=W[0].z*_v;  a[3]+=W[0].w*_v;  \
  a[4]+=W[1].x*_v;  a[5]+=W[1].y*_v;  a[6]+=W[1].z*_v;  a[7]+=W[1].w*_v;  \
  a[8]+=W[2].x*_v;  a[9]+=W[2].y*_v;  a[10]+=W[2].z*_v; a[11]+=W[2].w*_v; \
  a[12]+=W[3].x*_v; a[13]+=W[3].y*_v; a[14]+=W[3].z*_v; a[15]+=W[3].w*_v; \
  a[16]+=W[4].x*_v; a[17]+=W[4].y*_v; a[18]+=W[4].z*_v; a[19]+=W[4].w*_v; \
  a[20]+=W[5].x*_v; a[21]+=W[5].y*_v; a[22]+=W[5].z*_v; a[23]+=W[5].w*_v; } while(0)

// ---------------- colstats(x) for BN1 + edge histogram ----------------
__global__ void __launch_bounds__(256) k_pre(
        const float* __restrict__ x, float* __restrict__ s1,
        const int* __restrict__ ei, int E, int* __restrict__ counts) {
    int t = threadIdx.x;
    int c = t % C_IN;
    int r0 = blockIdx.x * 2 + t / C_IN;
    float s = 0.f, sq = 0.f;
    for (int r = r0; r < N_NODES; r += 512) {
        float v = x[(size_t)r * C_IN + c];
        s += v; sq += v * v;
    }
    atomicAdd(&s1[c], s);
    atomicAdd(&s1[C_IN + c], sq);
    for (int e = blockIdx.x * 256 + t; e < E; e += 256 * 256)
        atomicAdd(&counts[ei[E + e]], 1);
}

// ---------------- input MLP: lrelu(bn1(x)) @ lin1_w (+ BN2 stats) ----------------
__global__ void __launch_bounds__(256) k_mlp1(
        const float* __restrict__ x, const float* __restrict__ s1,
        const float* __restrict__ g1, const float* __restrict__ b1,
        const float* __restrict__ w1, float* __restrict__ hpre,
        float* __restrict__ s2sh) {
    __shared__ float sAB[2][C_IN];
    __shared__ float sx[32][C_IN + 4];
    __shared__ float sw[C_IN][C_W];
    const int t = threadIdx.x;
    const int row0 = blockIdx.x * 32;
    if (t < C_IN) {
        float mean = s1[t] * (1.f / N_NODES);
        float var = s1[C_IN + t] * (1.f / N_NODES) - mean * mean;
        float a = g1[t] * rsqrtf(var + 1e-5f);
        sAB[0][t] = a; sAB[1][t] = b1[t] - mean * a;
    }
    for (int idx = t; idx < C_IN * C_W; idx += 256)
        sw[idx / C_W][idx % C_W] = w1[idx];
    __syncthreads();
    for (int idx = t; idx < 32 * 32; idx += 256) {
        int r = idx >> 5, cq = idx & 31;
        float4 v = *(const float4*)&x[(size_t)(row0 + r) * C_IN + cq * 4];
        float* d = &sx[r][cq * 4];
        float a0 = sAB[0][cq*4+0]*v.x + sAB[1][cq*4+0];
        float a1 = sAB[0][cq*4+1]*v.y + sAB[1][cq*4+1];
        float a2 = sAB[0][cq*4+2]*v.z + sAB[1][cq*4+2];
        float a3 = sAB[0][cq*4+3]*v.w + sAB[1][cq*4+3];
        d[0] = a0 >= 0.f ? a0 : 0.1f * a0;
        d[1] = a1 >= 0.f ? a1 : 0.1f * a1;
        d[2] = a2 >= 0.f ? a2 : 0.1f * a2;
        d[3] = a3 >= 0.f ? a3 : 0.1f * a3;
    }
    __syncthreads();
    const int r = t >> 3, c0 = (t & 7) * 4;
    float ac0 = 0.f, ac1 = 0.f, ac2 = 0.f, ac3 = 0.f;
    #pragma unroll 8
    for (int cc = 0; cc < C_IN; ++cc) {
        float xv = sx[r][cc];
        float4 wv = *(const float4*)&sw[cc][c0];
        ac0 += xv * wv.x; ac1 += xv * wv.y; ac2 += xv * wv.z; ac3 += xv * wv.w;
    }
    float4 o; o.x = ac0; o.y = ac1; o.z = ac2; o.w = ac3;
    *(float4*)&hpre[(size_t)(row0 + r) * C_W + c0] = o;
    __syncthreads();
    sx[r][c0] = ac0; sx[r][c0+1] = ac1; sx[r][c0+2] = ac2; sx[r][c0+3] = ac3;
    __syncthreads();
    if (t < C_W) {
        float s = 0.f, sq = 0.f;
        #pragma unroll
        for (int rr = 0; rr < 32; ++rr) {
            float v = sx[rr][t];
            s += v; sq += v * v;
        }
        int sh = (blockIdx.x & 7) * 64;
        atomicAdd(&s2sh[sh + t], s);
        atomicAdd(&s2sh[sh + C_W + t], sq);
    }
}

// ---------------- single-block scan (1024 thr x 32 elems, int4) ----------------
__global__ void __launch_bounds__(1024) k_scan(
        const int* __restrict__ counts, int* __restrict__ offsets,
        int* __restrict__ cursor) {
    __shared__ int sblk[1024];
    const int t = threadIdx.x;
    const int base = t * 32;
    const int4* cp = (const int4*)(counts + base);
    int loc[32];
    int s = 0;
    #pragma unroll
    for (int q = 0; q < 8; ++q) {
        int4 v = cp[q];
        loc[q*4+0] = s; s += v.x;
        loc[q*4+1] = s; s += v.y;
        loc[q*4+2] = s; s += v.z;
        loc[q*4+3] = s; s += v.w;
    }
    sblk[t] = s;
    __syncthreads();
    for (int d = 1; d < 1024; d <<= 1) {
        int u = (t >= d) ? sblk[t - d] : 0;
        __syncthreads();
        sblk[t] += u;
        __syncthreads();
    }
    const int blockbase = sblk[t] - s;
    #pragma unroll
    for (int q = 0; q < 8; ++q) {
        int4 o;
        o.x = blockbase + loc[q*4+0];
        o.y = blockbase + loc[q*4+1];
        o.z = blockbase + loc[q*4+2];
        o.w = blockbase + loc[q*4+3];
        ((int4*)(offsets + base))[q] = o;
        ((int4*)(cursor + base))[q] = o;
    }
    if (t == 1023) offsets[N_NODES] = sblk[1023];
}

// ---------------- edge kernel: WeightNet + scatter to CSR slots ----------------
__global__ void __launch_bounds__(256) k_edge(
        const int* __restrict__ ei, int E,
        const float* __restrict__ pos, const float* __restrict__ ori,
        const int* __restrict__ seq,
        const float* __restrict__ wnw, const float* __restrict__ wnb,
        int* __restrict__ cursor, int* __restrict__ srcPerm,
        float* __restrict__ wPerm) {
    __shared__ float sWnw[11][169];
    __shared__ float sWnb[11][24];
    const int t = threadIdx.x;
    for (int idx = t; idx < 11 * 168; idx += 256)
        sWnw[idx / 168][idx % 168] = wnw[idx];
    for (int idx = t; idx < 11 * 24; idx += 256)
        sWnb[idx / 24][idx % 24] = wnb[idx];
    __syncthreads();
    const int e = blockIdx.x * 256 + t;
    if (e >= E) return;
    const int src = ei[e];
    const int dst = ei[E + e];
    int ds = seq[src] - seq[dst];
    ds = ds < -SS ? -SS : (ds > SS ? SS : ds);
    const int sb = ds + SS;
    float dx = pos[src * 3 + 0] - pos[dst * 3 + 0];
    float dy = pos[src * 3 + 1] - pos[dst * 3 + 1];
    float dz = pos[src * 3 + 2] - pos[dst * 3 + 2];
    float dist = sqrtf(dx * dx + dy * dy + dz * dz);
    float inv = 1.f / (dist + 1e-9f);
    float ux = dx * inv, uy = dy * inv, uz = dz * inv;
    float b0 = ori[src * 9 + 0], b1 = ori[src * 9 + 1], b2 = ori[src * 9 + 2];
    float delta[7];
    #pragma unroll
    for (int r = 0; r < 3; ++r) {
        float m0 = ori[dst * 9 + r * 3 + 0];
        float m1 = ori[dst * 9 + r * 3 + 1];
        float m2 = ori[dst * 9 + r * 3 + 2];
        delta[r]     = m0 * ux + m1 * uy + m2 * uz;
        delta[3 + r] = m0 * b0 + m1 * b1 + m2 * b2;
    }
    delta[6] = dist * 0.125f;
    float w[KK];
    #pragma unroll
    for (int k = 0; k < KK; ++k) {
        float acc = sWnb[sb][k];
        #pragma unroll
        for (int f = 0; f < 7; ++f)
            acc += delta[f] * sWnw[sb][f * 24 + k];
        w[k] = acc >= 0.f ? acc : 0.2f * acc;
    }
    const int p = atomicAdd(&cursor[dst], 1);
    srcPerm[p] = src;
    float4* wp = (float4*)(wPerm + (size_t)p * KK);
    #pragma unroll
    for (int q = 0; q < 6; ++q) {
        float4 o; o.x = w[q*4]; o.y = w[q*4+1]; o.z = w[q*4+2]; o.w = w[q*4+3];
        wp[q] = o;
    }
}

// ---------------- aggregation + conv projection (+ BN3 stats) ----------------
__global__ void __launch_bounds__(256) k_node(
    const int* __restrict__ offsets, const int* __restrict__ srcPerm,
    const float* __restrict__ wPerm, const float* __restrict__ hpre,
    const float* __restrict__ s2sh, const float* __restrict__ g2,
    const float* __restrict__ b2, const float* __restrict__ convw,
    float* __restrict__ convout, float* __restrict__ s3sh) {
    __shared__ float sA2[C_W], sB2[C_W];
    __shared__ int sOff[GG + 1];
    __shared__ float sAgg[GG][KK * C_W];
    __shared__ float sRv[GG][C_W], sRq[GG][C_W];
    const int i0 = blockIdx.x * GG;
    const int t = threadIdx.x;
    if (t < C_W) {
        float s = 0.f, sq = 0.f;
        #pragma unroll
        for (int j = 0; j < 8; ++j) {
            s  += s2sh[j * 64 + t];
            sq += s2sh[j * 64 + C_W + t];
        }
        float mean = s * (1.f / N_NODES);
        float var = sq * (1.f / N_NODES) - mean * mean;
        float a = g2[t] * rsqrtf(var + 1e-5f);
        sA2[t] = a; sB2[t] = b2[t] - mean * a;
    }
    if (t <= GG) sOff[t] = offsets[i0 + t];
    __syncthreads();
    const int g = t >> 5, c = t & 31;
    const float bnA = sA2[c], bnB = sB2[c];
    const int beg = sOff[g], end = sOff[g + 1];
    float a[KK];
    #pragma unroll
    for (int k = 0; k < KK; ++k) a[k] = 0.f;

    for (int cb = beg; cb < end; cb += 32) {
        const int m = min(32, end - cb);
        // coalesced load of up to 32 src indices into lanes
        int srcL = (cb + c < end) ? srcPerm[cb + c] : 0;
        int j = 0;
        for (; j + 4 <= m; j += 4) {
            int s0 = __shfl(srcL, j + 0, 32);
            int s1 = __shfl(srcL, j + 1, 32);
            int s2 = __shfl(srcL, j + 2, 32);
            int s3 = __shfl(srcL, j + 3, 32);
            float h0 = hpre[(size_t)s0 * C_W + c];
            float h1 = hpre[(size_t)s1 * C_W + c];
            float h2 = hpre[(size_t)s2 * C_W + c];
            float h3 = hpre[(size_t)s3 * C_W + c];
            float4 wa[6], wb[6], wc[6], wd[6];
            const float* wbase = wPerm + (size_t)(cb + j) * KK;
            LD6(wa, wbase);
            LD6(wb, wbase + KK);
            LD6(wc, wbase + 2 * KK);
            LD6(wd, wbase + 3 * KK);
            float v0 = bnA * h0 + bnB; v0 = v0 >= 0.f ? v0 : 0.1f * v0;
            float v1 = bnA * h1 + bnB; v1 = v1 >= 0.f ? v1 : 0.1f * v1;
            float v2 = bnA * h2 + bnB; v2 = v2 >= 0.f ? v2 : 0.1f * v2;
            float v3 = bnA * h3 + bnB; v3 = v3 >= 0.f ? v3 : 0.1f * v3;
            ACC24(wa, v0);
            ACC24(wb, v1);
            ACC24(wc, v2);
            ACC24(wd, v3);
        }
        for (; j < m; ++j) {
            int s0 = __shfl(srcL, j, 32);
            float h0 = hpre[(size_t)s0 * C_W + c];
            float4 wa[6];
            LD6(wa, wPerm + (size_t)(cb + j) * KK);
            float v0 = bnA * h0 + bnB; v0 = v0 >= 0.f ? v0 : 0.1f * v0;
            ACC24(wa, v0);
        }
    }
    #pragma unroll
    for (int k = 0; k < KK; ++k) sAgg[g][k * C_W + c] = a[k];
    __syncthreads();
    float p0 = 0.f, p1 = 0.f;
    for (int r = 0; r < KK * C_W; r += 8) {
        float4 v0 = *(const float4*)&sAgg[g][r];
        float4 v1 = *(const float4*)&sAgg[g][r + 4];
        p0 += v0.x * convw[(r + 0) * 32 + c] + v0.y * convw[(r + 1) * 32 + c]
            + v0.z * convw[(r + 2) * 32 + c] + v0.w * convw[(r + 3) * 32 + c];
        p1 += v1.x * convw[(r + 4) * 32 + c] + v1.y * convw[(r + 5) * 32 + c]
            + v1.z * convw[(r + 6) * 32 + c] + v1.w * convw[(r + 7) * 32 + c];
    }
    float v = p0 + p1;
    convout[(size_t)(i0 + g) * C_W + c] = v;
    sRv[g][c] = v; sRq[g][c] = v * v;
    __syncthreads();
    if (t < 64) {
        int cc = t & 31;
        bool isq = t >= C_W;
        float s = 0.f;
        #pragma unroll
        for (int gg = 0; gg < GG; ++gg)
            s += isq ? sRq[gg][cc] : sRv[gg][cc];
        atomicAdd(&s3sh[(blockIdx.x & 7) * 64 + t], s);
    }
}

// ---------------- output: lrelu(bn3(conv)) @ lin2_w + x (float4) ----------------
__global__ void __launch_bounds__(256) k_out(
        const float* __restrict__ conv, const float* __restrict__ s3sh,
        const float* __restrict__ g3, const float* __restrict__ b3,
        const float* __restrict__ w2, const float* __restrict__ x,
        float* __restrict__ out) {
    __shared__ float sAB[2][C_W];
    __shared__ float sh[8][C_W];
    __shared__ float sw2[C_W][C_IN];
    const int t = threadIdx.x;
    const int row0 = blockIdx.x * 8;
    if (t < C_W) {
        float s = 0.f, sq = 0.f;
        #pragma unroll
        for (int j = 0; j < 8; ++j) {
            s  += s3sh[j * 64 + t];
            sq += s3sh[j * 64 + C_W + t];
        }
        float mean = s * (1.f / N_NODES);
        float var = sq * (1.f / N_NODES) - mean * mean;
        float a = g3[t] * rsqrtf(var + 1e-5f);
        sAB[0][t] = a; sAB[1][t] = b3[t] - mean * a;
    }
    for (int idx = t; idx < C_W * C_IN; idx += 256)
        sw2[idx >> 7][idx & 127] = w2[idx];
    __syncthreads();
    {
        float v = conv[(size_t)row0 * C_W + t];
        int r = t >> 5, cc = t & 31;
        v = sAB[0][cc] * v + sAB[1][cc];
        sh[r][cc] = v >= 0.f ? v : 0.1f * v;
    }
    __syncthreads();
    const int r = t >> 5, c4 = (t & 31) * 4;
    float4 acc = *(const float4*)&x[(size_t)(row0 + r) * C_IN + c4];
    #pragma unroll 8
    for (int cw = 0; cw < C_W; ++cw) {
        float hv = sh[r][cw];
        float4 wv = *(const float4*)&sw2[cw][c4];
        acc.x += hv * wv.x; acc.y += hv * wv.y;
        acc.z += hv * wv.z; acc.w += hv * wv.w;
    }
    *(float4*)&out[(size_t)(row0 + r) * C_IN + c4] = acc;
}

extern "C" void kernel_launch(void* const* d_in, const int* in_sizes, int n_in,
                              void* d_out, int out_size, void* d_ws, size_t ws_size,
                              hipStream_t stream) {
    const float* x     = (const float*)d_in[0];
    const float* pos   = (const float*)d_in[1];
    const float* ori   = (const float*)d_in[2];
    const int*   seq   = (const int*)d_in[3];
    const int*   ei    = (const int*)d_in[4];
    const float* bn1g  = (const float*)d_in[5];
    const float* bn1b  = (const float*)d_in[6];
    const float* lin1w = (const float*)d_in[7];
    const float* bn2g  = (const float*)d_in[8];
    const float* bn2b  = (const float*)d_in[9];
    const float* wnw   = (const float*)d_in[10];
    const float* wnb   = (const float*)d_in[11];
    const float* convw = (const float*)d_in[12];
    const float* bn3g  = (const float*)d_in[13];
    const float* bn3b  = (const float*)d_in[14];
    const float* lin2w = (const float*)d_in[15];
    float* out = (float*)d_out;
    const int E = in_sizes[4] / 2;

    char* wsb = (char*)d_ws;
    size_t off = 0;
    auto alloc = [&](size_t bytes) {
        void* p = wsb + off;
        off = (off + bytes + 255) & ~(size_t)255;
        return p;
    };
    float* s1      = (float*)alloc(256 * 4);
    float* s2sh    = (float*)alloc(512 * 4);
    float* s3sh    = (float*)alloc(512 * 4);
    int*   counts  = (int*)alloc((size_t)N_NODES * 4);
    size_t zero_bytes = off;
    int*   offsets = (int*)alloc(((size_t)N_NODES + 1) * 4);
    int*   cursor  = (int*)alloc((size_t)N_NODES * 4);
    int*   srcPerm = (int*)alloc((size_t)E * 4);
    float* hpre    = (float*)alloc((size_t)N_NODES * C_W * 4);
    float* convo   = (float*)alloc((size_t)N_NODES * C_W * 4);
    float* wPerm   = (float*)alloc((size_t)E * KK * 4);

    hipMemsetAsync(wsb, 0, zero_bytes, stream);

    k_pre<<<256, 256, 0, stream>>>(x, s1, ei, E, counts);
    k_scan<<<1, 1024, 0, stream>>>(counts, offsets, cursor);
    k_edge<<<(E + 255) / 256, 256, 0, stream>>>(ei, E, pos, ori, seq, wnw, wnb,
                                                cursor, srcPerm, wPerm);
    k_mlp1<<<N_NODES / 32, 256, 0, stream>>>(x, s1, bn1g, bn1b, lin1w, hpre, s2sh);
    k_node<<<N_NODES / GG, 256, 0, stream>>>(offsets, srcPerm, wPerm, hpre,
                                             s2sh, bn2g, bn2b, convw, convo, s3sh);
    k_out<<<N_NODES / 8, 256, 0, stream>>>(convo, s3sh, bn3g, bn3b, lin2w, x, out);
}